// Round 16
// baseline (79.705 us; speedup 1.0000x reference)
//
#include <hip/hip_runtime.h>
#include <math.h>

namespace {

constexpr int SEQ    = 4;
constexpr int WCHUNK = 64 * SEQ;   // 256 elements = one wave = one block

// LDS float-index region offsets (single wave, 10 KB -> 16 blocks/CU).
constexpr int GY_F  = 0;           // 768 floats (3 KB)  gyro | vel out
constexpr int AC_F  = 768;         // 768 floats (3 KB)  acc  | pos out
constexpr int GT_F  = 1536;        // 1024 floats (4 KB) gt   | rot out
constexpr int LDS_F = 2560;        // 10 KB total

struct V3 { float x, y, z; };
struct Q4 { float x, y, z, w; };
struct St { Q4 q; V3 s; V3 p; float T; float pad; }; // 48 B (aggs/k_pref)

__device__ __forceinline__ Q4 qmul(const Q4 a, const Q4 b) {
  Q4 r;
  r.x = a.w*b.x + b.w*a.x + a.y*b.z - a.z*b.y;
  r.y = a.w*b.y + b.w*a.y + a.z*b.x - a.x*b.z;
  r.z = a.w*b.z + b.w*a.z + a.x*b.y - a.y*b.x;
  r.w = a.w*b.w - a.x*b.x - a.y*b.y - a.z*b.z;
  return r;
}

__device__ __forceinline__ V3 qrot(const Q4 q, const V3 v) {
  float tx = q.y*v.z - q.z*v.y + q.w*v.x;
  float ty = q.z*v.x - q.x*v.z + q.w*v.y;
  float tz = q.x*v.y - q.y*v.x + q.w*v.z;
  V3 r;
  r.x = v.x + 2.0f*(q.y*tz - q.z*ty);
  r.y = v.y + 2.0f*(q.z*tx - q.x*tz);
  r.z = v.z + 2.0f*(q.x*ty - q.y*tx);
  return r;
}

__device__ __forceinline__ St combine(const St a, const St b) {
  St r;
  r.q = qmul(a.q, b.q);
  V3 rs = qrot(a.q, b.s);
  r.s.x = a.s.x + rs.x;
  r.s.y = a.s.y + rs.y;
  r.s.z = a.s.z + rs.z;
  V3 rp = qrot(a.q, b.p);
  r.p.x = a.p.x + a.s.x*b.T + rp.x;
  r.p.y = a.p.y + a.s.y*b.T + rp.y;
  r.p.z = a.p.z + a.s.z*b.T + rp.z;
  r.T = a.T + b.T;
  r.pad = 0.0f;
  return r;
}

__device__ __forceinline__ St identity_st() {
  St r;
  r.q = {0.0f, 0.0f, 0.0f, 1.0f};
  r.s = {0.0f, 0.0f, 0.0f};
  r.p = {0.0f, 0.0f, 0.0f};
  r.T = 0.0f; r.pad = 0.0f;
  return r;
}

// slim element: dr quaternion, s = qrot(dr, a)*dt, dt  (e.p == e.s*dt/2
// implicitly). θ ≤ ~0.02: 2-term Taylor fp32-exact, no libm.
struct El { Q4 q; V3 s; float dt; };

__device__ __forceinline__ El elem_state(float dt, V3 w, V3 ac, Q4 gt) {
  float px = w.x*dt, py = w.y*dt, pz = w.z*dt;
  float t2 = px*px + py*py + pz*pz;                        // θ²
  float k  = 0.5f + t2*(-1.0f/48.0f  + t2*(1.0f/3840.0f)); // sin(θ/2)/θ
  float cw = 1.0f + t2*(-0.125f      + t2*(1.0f/384.0f));  // cos(θ/2)
  Q4 dr = { px*k, py*k, pz*k, cw };
  Q4 gi = { -gt.x, -gt.y, -gt.z, gt.w };
  V3 g  = { 0.0f, 0.0f, 9.81007f };
  V3 gr = qrot(gi, g);
  V3 a  = { ac.x - gr.x, ac.y - gr.y, ac.z - gr.z };
  V3 ra = qrot(dr, a);
  El e;
  e.q = dr;
  e.s = { ra.x*dt, ra.y*dt, ra.z*dt };
  e.dt = dt;
  return e;
}

__device__ __forceinline__ Q4 shfl_up_q(const Q4 v, int d) {
  return { __shfl_up(v.x,d), __shfl_up(v.y,d), __shfl_up(v.z,d), __shfl_up(v.w,d) };
}
__device__ __forceinline__ V3 shfl_up_v(const V3 v, int d) {
  return { __shfl_up(v.x,d), __shfl_up(v.y,d), __shfl_up(v.z,d) };
}

__device__ __forceinline__ St shfl_up_st(const St& v, int d) {
  St r;
  r.q.x = __shfl_up(v.q.x, d); r.q.y = __shfl_up(v.q.y, d);
  r.q.z = __shfl_up(v.q.z, d); r.q.w = __shfl_up(v.q.w, d);
  r.s.x = __shfl_up(v.s.x, d); r.s.y = __shfl_up(v.s.y, d);
  r.s.z = __shfl_up(v.s.z, d);
  r.p.x = __shfl_up(v.p.x, d); r.p.y = __shfl_up(v.p.y, d);
  r.p.z = __shfl_up(v.p.z, d);
  r.T   = __shfl_up(v.T, d);   r.pad = 0.0f;
  return r;
}

__device__ __forceinline__ St bcast_st(const St& v, int src) {
  St r;
  r.q.x = __shfl(v.q.x, src); r.q.y = __shfl(v.q.y, src);
  r.q.z = __shfl(v.q.z, src); r.q.w = __shfl(v.q.w, src);
  r.s.x = __shfl(v.s.x, src); r.s.y = __shfl(v.s.y, src);
  r.s.z = __shfl(v.s.z, src);
  r.p.x = __shfl(v.p.x, src); r.p.y = __shfl(v.p.y, src);
  r.p.z = __shfl(v.p.z, src);
  r.T   = __shfl(v.T, src);   r.pad = 0.0f;
  return r;
}

// Swizzle: XOR byte-addr bits 4-5 with bits 8-9 (involution, 16B-preserving,
// bijective per 256 B block). Applied consistently on LDS WRITE and READ
// sides (reg-staging: both sides go through L4, so the mapping is just a
// bank-spread for the stride-64B patterns).
__device__ __forceinline__ int swz(int byteoff) {
  return byteoff ^ (((byteoff >> 8) & 3) << 4);
}
__device__ __forceinline__ float4& L4(float* lds, int fidx) {
  return *reinterpret_cast<float4*>(reinterpret_cast<char*>(lds) + swz(fidx << 2));
}

struct Compressed { float cq[12]; float cs[12]; float cdt[4]; };
struct Seg { Q4 q; V3 s; V3 p; float T; };
struct ScanRes { Q4 qex, qin; V3 sex, sin; V3 pex, pin; float Tex, Tin; };

// Reg-stage: dense global float4 loads -> swizzled LDS writes. The compiler
// emits INCREMENTAL vmcnt(N) waits before each ds_write (no vmcnt(0) cliff),
// and gy reads can start while gt loads are still in flight. Wave-private
// LDS: intra-wave ds ordering handled by compiler lgkmcnt (no barrier).
__device__ __forceinline__ void reg_stage(float* lds, int t,
    const float* gyp, const float* acp, const float* gtp, size_t base) {
  const float4* ggy = (const float4*)(gyp + base*3);
  const float4* gac = (const float4*)(acp + base*3);
  const float4* ggt = (const float4*)(gtp + base*4);
  float4 rgy0 = ggy[t], rgy1 = ggy[t+64], rgy2 = ggy[t+128];
  float4 rac0 = gac[t], rac1 = gac[t+64], rac2 = gac[t+128];
  L4(lds, GY_F + 4*t)       = rgy0;
  L4(lds, GY_F + 4*(t+64))  = rgy1;
  L4(lds, GY_F + 4*(t+128)) = rgy2;
  float4 rgt0 = ggt[t], rgt1 = ggt[t+64], rgt2 = ggt[t+128], rgt3 = ggt[t+192];
  L4(lds, AC_F + 4*t)       = rac0;
  L4(lds, AC_F + 4*(t+64))  = rac1;
  L4(lds, AC_F + 4*(t+128)) = rac2;
  L4(lds, GT_F + 4*t)       = rgt0;
  L4(lds, GT_F + 4*(t+64))  = rgt1;
  L4(lds, GT_F + 4*(t+128)) = rgt2;
  L4(lds, GT_F + 4*(t+192)) = rgt3;
}

// read 4 elements' inputs from staged LDS, build slim states + thread-local
// segment aggregate.
__device__ __forceinline__ Seg build_slim(float* lds, int t,
                                          float4 dt4, Compressed& C) {
  float gy[12], ac[12], gq[16];
  #pragma unroll
  for (int j = 0; j < 3; ++j) ((float4*)gy)[j] = L4(lds, GY_F + 12*t + 4*j);
  #pragma unroll
  for (int j = 0; j < 3; ++j) ((float4*)ac)[j] = L4(lds, AC_F + 12*t + 4*j);
  #pragma unroll
  for (int j = 0; j < 4; ++j) ((float4*)gq)[j] = L4(lds, GT_F + 16*t + 4*j);
  const float dtv[4] = {dt4.x, dt4.y, dt4.z, dt4.w};
  Seg s;
  #pragma unroll
  for (int i = 0; i < SEQ; ++i) {
    El e = elem_state(dtv[i],
               {gy[3*i], gy[3*i+1], gy[3*i+2]},
               {ac[3*i], ac[3*i+1], ac[3*i+2]},
               {gq[4*i], gq[4*i+1], gq[4*i+2], gq[4*i+3]});
    C.cq[3*i] = e.q.x; C.cq[3*i+1] = e.q.y; C.cq[3*i+2] = e.q.z;
    C.cs[3*i] = e.s.x; C.cs[3*i+1] = e.s.y; C.cs[3*i+2] = e.s.z;
    C.cdt[i]  = e.dt;
    if (i == 0) {
      s.q = e.q; s.s = e.s;
      float h = 0.5f*e.dt;
      s.p = { e.s.x*h, e.s.y*h, e.s.z*h };
      s.T = e.dt;
    } else {
      V3 v = qrot(s.q, e.s);
      float h = 0.5f*e.dt;
      s.p.x += s.s.x*e.dt + v.x*h;
      s.p.y += s.s.y*e.dt + v.y*h;
      s.p.z += s.s.z*e.dt + v.z*h;
      s.s.x += v.x; s.s.y += v.y; s.s.z += v.z;
      s.q = qmul(s.q, e.q);
      s.T += e.dt;
    }
  }
  return s;
}

// split wave scan (order-preserving): quaternion scan + additive scans.
__device__ __forceinline__ ScanRes wave_split_scan(int t, const Seg& sg) {
  ScanRes r;
  Q4 qin = sg.q;
  #pragma unroll
  for (int d = 1; d < 64; d <<= 1) {
    Q4 o = shfl_up_q(qin, d);
    if (t >= d) qin = qmul(o, qin);
  }
  Q4 qex = shfl_up_q(qin, 1);
  if (t == 0) qex = {0.0f, 0.0f, 0.0f, 1.0f};
  V3 v = qrot(qex, sg.s);
  V3 sin_ = v;
  #pragma unroll
  for (int d = 1; d < 64; d <<= 1) {
    V3 o = shfl_up_v(sin_, d);
    if (t >= d) { sin_.x += o.x; sin_.y += o.y; sin_.z += o.z; }
  }
  V3 sex = shfl_up_v(sin_, 1);
  if (t == 0) sex = {0.0f, 0.0f, 0.0f};
  float Tin = sg.T;
  #pragma unroll
  for (int d = 1; d < 64; d <<= 1) {
    float o = __shfl_up(Tin, d);
    if (t >= d) Tin += o;
  }
  float Tex = __shfl_up(Tin, 1);
  if (t == 0) Tex = 0.0f;
  V3 w = qrot(qex, sg.p);
  V3 u = { w.x + sex.x*sg.T, w.y + sex.y*sg.T, w.z + sex.z*sg.T };
  V3 pin = u;
  #pragma unroll
  for (int d = 1; d < 64; d <<= 1) {
    V3 o = shfl_up_v(pin, d);
    if (t >= d) { pin.x += o.x; pin.y += o.y; pin.z += o.z; }
  }
  V3 pex = shfl_up_v(pin, 1);
  if (t == 0) pex = {0.0f, 0.0f, 0.0f};
  r.qex = qex; r.qin = qin;
  r.sex = sex; r.sin = sin_;
  r.pex = pex; r.pin = pin;
  r.Tex = Tex; r.Tin = Tin;
  return r;
}

// Kernel 1: per-chunk aggregates. ONE WAVE PER BLOCK, reg-staged.
__global__ __launch_bounds__(64, 4) void k_agg(
    const float* __restrict__ dtp, const float* __restrict__ gyp,
    const float* __restrict__ acp, const float* __restrict__ gtp,
    St* __restrict__ aggs)
{
  __shared__ __align__(16) float lds[LDS_F];
  const int t = threadIdx.x;          // == lane
  const size_t base = (size_t)blockIdx.x * WCHUNK;

  float4 dt4 = ((const float4*)(dtp + base))[t];
  reg_stage(lds, t, gyp, acp, gtp, base);
  // no barrier: wave-private LDS, compiler orders ds ops via lgkmcnt

  Compressed C;
  Seg s = build_slim(lds, t, dt4, C);
  ScanRes R = wave_split_scan(t, s);

  if (t == 63) {
    St a;
    a.q = R.qin; a.s = R.sin; a.p = R.pin; a.T = R.Tin; a.pad = 0.0f;
    aggs[blockIdx.x] = a;
  }
}

// Kernel 2: exclusive chunk prefixes. One wave per batch row; cpb in
// 64-wide windows with carry. (Unchanged.)
__global__ __launch_bounds__(64) void k_pref(
    const St* __restrict__ aggs, const float* __restrict__ irp,
    float* __restrict__ prefb, int cpb)
{
  const int b = blockIdx.x;
  const int lane = threadIdx.x & 63;

  St carry = identity_st();
  carry.q = { irp[b*4+0], irp[b*4+1], irp[b*4+2], irp[b*4+3] };

  const int nw = (cpb + 63) >> 6;
  for (int w = 0; w < nw; ++w) {
    const int idx = (w << 6) + lane;
    St A = identity_st();
    if (idx < cpb) A = aggs[(size_t)b*cpb + idx];
    #pragma unroll
    for (int d = 1; d < 64; d <<= 1) {
      St o = shfl_up_st(A, d);
      if (lane >= d) A = combine(o, A);
    }
    St ex = shfl_up_st(A, 1);
    St P = (lane == 0) ? carry : combine(carry, ex);
    if (idx < cpb) {
      float4* pp = (float4*)(prefb + ((size_t)b*cpb + idx)*12);
      pp[0] = make_float4(P.q.x, P.q.y, P.q.z, P.q.w);
      pp[1] = make_float4(P.s.x, P.s.y, P.s.z, P.p.x);
      pp[2] = make_float4(P.p.y, P.p.z, P.T, 0.0f);
    }
    carry = combine(carry, bcast_st(A, 63));
  }
}

// Kernel 3: emit. ONE WAVE PER BLOCK, reg-staged (incremental vmcnt waits,
// no stage barrier), split scan + split emit, outputs restaged through LDS
// (regions reused: gt->rot, gy->vel, ac->pos), dense stores.
__global__ __launch_bounds__(64, 4) void k_emit(
    const float* __restrict__ dtp, const float* __restrict__ gyp,
    const float* __restrict__ acp, const float* __restrict__ gtp,
    const float* __restrict__ prefb,
    const float* __restrict__ ivp, const float* __restrict__ ipp,
    float* __restrict__ out, int F, int cpb, int B)
{
  __shared__ __align__(16) float lds[LDS_F];
  const int t = threadIdx.x;          // == lane
  const int cid = blockIdx.x;
  const int b = cid / cpb;
  const size_t base = (size_t)cid * WCHUNK;

  // uniform loads first: wave prefix + per-batch vectors
  Q4 Pq; V3 Ps, Pp; float PT;
  {
    const float4* pp = (const float4*)(prefb + (size_t)cid*12);
    float4 a = pp[0], bb = pp[1], cc = pp[2];
    Pq = {a.x, a.y, a.z, a.w};
    Ps = {bb.x, bb.y, bb.z};
    Pp = {bb.w, cc.x, cc.y};
    PT = cc.z;
  }
  V3 iv = { ivp[b*3+0], ivp[b*3+1], ivp[b*3+2] };
  V3 ip = { ipp[b*3+0], ipp[b*3+1], ipp[b*3+2] };

  float4 dt4 = ((const float4*)(dtp + base))[t];
  reg_stage(lds, t, gyp, acp, gtp, base);
  // no barrier: compiler orders ds_write->ds_read via lgkmcnt, vmcnt waits
  // are incremental per-ds_write

  Compressed C;
  Seg s = build_slim(lds, t, dt4, C);
  ScanRes S = wave_split_scan(t, s);

  // apply chunk prefix to this lane's exclusive state: X = P ∘ ex
  Q4 Xq = qmul(Pq, S.qex);
  V3 rs = qrot(Pq, S.sex);
  V3 Xs = { Ps.x + rs.x, Ps.y + rs.y, Ps.z + rs.z };
  V3 rp = qrot(Pq, S.pex);
  V3 Xp = { Pp.x + Ps.x*S.Tex + rp.x, Pp.y + Ps.y*S.Tex + rp.y,
            Pp.z + Ps.z*S.Tex + rp.z };
  float XT = PT + S.Tex;

  __syncthreads();   // cheap (vmcnt already 0): input reads done before overwrite

  // split emit loop into LDS (rot->GT region, vel->GY, pos->AC)
  {
    Q4 qr = Xq; V3 sr = Xs; V3 pr = Xp; float Tr = XT;
    float velb[12], posb[12];
    #pragma unroll
    for (int i = 0; i < SEQ; ++i) {
      float qx = C.cq[3*i], qy = C.cq[3*i+1], qz = C.cq[3*i+2];
      Q4 eq = { qx, qy, qz, sqrtf(fmaxf(1.0f - qx*qx - qy*qy - qz*qz, 0.0f)) };
      V3 es = { C.cs[3*i], C.cs[3*i+1], C.cs[3*i+2] };
      float dt = C.cdt[i], h = 0.5f*dt;
      V3 vv = qrot(qr, es);
      V3 pn = { pr.x + sr.x*dt + vv.x*h,
                pr.y + sr.y*dt + vv.y*h,
                pr.z + sr.z*dt + vv.z*h };
      V3 sn = { sr.x + vv.x, sr.y + vv.y, sr.z + vv.z };
      Q4 qn = qmul(qr, eq);
      float Tn = Tr + dt;
      L4(lds, GT_F + 4*(4*t + i)) = make_float4(qn.x, qn.y, qn.z, qn.w);
      velb[3*i+0] = iv.x + sn.x;
      velb[3*i+1] = iv.y + sn.y;
      velb[3*i+2] = iv.z + sn.z;
      posb[3*i+0] = ip.x + iv.x*Tn + pn.x;
      posb[3*i+1] = ip.y + iv.y*Tn + pn.y;
      posb[3*i+2] = ip.z + iv.z*Tn + pn.z;
      qr = qn; sr = sn; pr = pn; Tr = Tn;
    }
    #pragma unroll
    for (int j = 0; j < 3; ++j) L4(lds, GY_F + 12*t + 4*j) = ((float4*)velb)[j];
    #pragma unroll
    for (int j = 0; j < 3; ++j) L4(lds, AC_F + 12*t + 4*j) = ((float4*)posb)[j];
  }
  __syncthreads();   // cheap: order LDS emit-writes vs cross-lane store-reads

  // dense stores
  const size_t BF = (size_t)B * (size_t)F;
  float4* grot = (float4*)out + base;
  float4* gvel = (float4*)(out + BF*4 + base*3);
  float4* gpos = (float4*)(out + BF*7 + base*3);
  #pragma unroll
  for (int k = 0; k < 4; ++k) grot[t + 64*k] = L4(lds, GT_F + 4*(t + 64*k));
  #pragma unroll
  for (int k = 0; k < 3; ++k) gvel[t + 64*k] = L4(lds, GY_F + 4*(t + 64*k));
  #pragma unroll
  for (int k = 0; k < 3; ++k) gpos[t + 64*k] = L4(lds, AC_F + 4*(t + 64*k));
}

} // namespace

extern "C" void kernel_launch(void* const* d_in, const int* in_sizes, int n_in,
                              void* d_out, int out_size, void* d_ws, size_t ws_size,
                              hipStream_t stream)
{
  (void)n_in; (void)out_size; (void)ws_size;

  const float* dtp = (const float*)d_in[0];
  const float* gyp = (const float*)d_in[1];
  const float* acp = (const float*)d_in[2];
  const float* gtp = (const float*)d_in[3];
  const float* irp = (const float*)d_in[4];
  const float* ivp = (const float*)d_in[5];
  const float* ipp = (const float*)d_in[6];
  float* out = (float*)d_out;

  const int B   = in_sizes[4] / 4;    // init_rot has B*4 elements
  const int F   = in_sizes[0] / B;    // dt has B*F elements
  const int cpb = F / WCHUNK;         // 128 for F=32768
  const int nchunk = B * cpb;         // 8192

  St*    aggs  = (St*)d_ws;
  float* prefb = (float*)((char*)d_ws + (size_t)nchunk * sizeof(St));

  k_agg <<<nchunk, 64, 0, stream>>>(dtp, gyp, acp, gtp, aggs);
  k_pref<<<B,      64, 0, stream>>>(aggs, irp, prefb, cpb);
  k_emit<<<nchunk, 64, 0, stream>>>(dtp, gyp, acp, gtp, prefb, ivp, ipp,
                                    out, F, cpb, B);
}

// Round 17
// 60.036 us; speedup vs baseline: 1.3276x; 1.3276x over previous
//
#include <hip/hip_runtime.h>
#include <math.h>

namespace {

constexpr int SEQ    = 4;
constexpr int WCHUNK = 64 * SEQ;   // 256 elements = one wave = one block

// LDS float-index region offsets, PER-BLOCK (single wave). All bases
// 1024 B-aligned so swizzle bits (8-9) match region-relative addressing.
constexpr int GY_F  = 0;           // 768 floats (3 KB)  gyro | vel out
constexpr int AC_F  = 768;         // 768 floats (3 KB)  acc  | pos out
constexpr int GT_F  = 1536;        // 1024 floats (4 KB) gt   | rot out
constexpr int LDS_F = 2560;        // 10 KB total -> 16 blocks/CU

struct V3 { float x, y, z; };
struct Q4 { float x, y, z, w; };
struct St { Q4 q; V3 s; V3 p; float T; float pad; }; // 48 B (k_pref/aggs)

__device__ __forceinline__ Q4 qmul(const Q4 a, const Q4 b) {
  Q4 r;
  r.x = a.w*b.x + b.w*a.x + a.y*b.z - a.z*b.y;
  r.y = a.w*b.y + b.w*a.y + a.z*b.x - a.x*b.z;
  r.z = a.w*b.z + b.w*a.z + a.x*b.y - a.y*b.x;
  r.w = a.w*b.w - a.x*b.x - a.y*b.y - a.z*b.z;
  return r;
}

__device__ __forceinline__ V3 qrot(const Q4 q, const V3 v) {
  float tx = q.y*v.z - q.z*v.y + q.w*v.x;
  float ty = q.z*v.x - q.x*v.z + q.w*v.y;
  float tz = q.x*v.y - q.y*v.x + q.w*v.z;
  V3 r;
  r.x = v.x + 2.0f*(q.y*tz - q.z*ty);
  r.y = v.y + 2.0f*(q.z*tx - q.x*tz);
  r.z = v.z + 2.0f*(q.x*ty - q.y*tx);
  return r;
}

__device__ __forceinline__ St combine(const St a, const St b) {
  St r;
  r.q = qmul(a.q, b.q);
  V3 rs = qrot(a.q, b.s);
  r.s.x = a.s.x + rs.x;
  r.s.y = a.s.y + rs.y;
  r.s.z = a.s.z + rs.z;
  V3 rp = qrot(a.q, b.p);
  r.p.x = a.p.x + a.s.x*b.T + rp.x;
  r.p.y = a.p.y + a.s.y*b.T + rp.y;
  r.p.z = a.p.z + a.s.z*b.T + rp.z;
  r.T = a.T + b.T;
  r.pad = 0.0f;
  return r;
}

__device__ __forceinline__ St identity_st() {
  St r;
  r.q = {0.0f, 0.0f, 0.0f, 1.0f};
  r.s = {0.0f, 0.0f, 0.0f};
  r.p = {0.0f, 0.0f, 0.0f};
  r.T = 0.0f; r.pad = 0.0f;
  return r;
}

// slim element: dr quaternion, s = qrot(dr, a)*dt, dt.  (e.p == e.s*dt/2
// implicitly; never materialized.)  θ ≤ ~0.02: 2-term Taylor fp32-exact.
struct El { Q4 q; V3 s; float dt; };

__device__ __forceinline__ El elem_state(float dt, V3 w, V3 ac, Q4 gt) {
  float px = w.x*dt, py = w.y*dt, pz = w.z*dt;
  float t2 = px*px + py*py + pz*pz;                        // θ²
  float k  = 0.5f + t2*(-1.0f/48.0f  + t2*(1.0f/3840.0f)); // sin(θ/2)/θ
  float cw = 1.0f + t2*(-0.125f      + t2*(1.0f/384.0f));  // cos(θ/2)
  Q4 dr = { px*k, py*k, pz*k, cw };
  Q4 gi = { -gt.x, -gt.y, -gt.z, gt.w };
  V3 g  = { 0.0f, 0.0f, 9.81007f };
  V3 gr = qrot(gi, g);
  V3 a  = { ac.x - gr.x, ac.y - gr.y, ac.z - gr.z };
  V3 ra = qrot(dr, a);
  El e;
  e.q = dr;
  e.s = { ra.x*dt, ra.y*dt, ra.z*dt };
  e.dt = dt;
  return e;
}

__device__ __forceinline__ Q4 shfl_up_q(const Q4 v, int d) {
  return { __shfl_up(v.x,d), __shfl_up(v.y,d), __shfl_up(v.z,d), __shfl_up(v.w,d) };
}
__device__ __forceinline__ V3 shfl_up_v(const V3 v, int d) {
  return { __shfl_up(v.x,d), __shfl_up(v.y,d), __shfl_up(v.z,d) };
}

__device__ __forceinline__ St shfl_up_st(const St& v, int d) {
  St r;
  r.q.x = __shfl_up(v.q.x, d); r.q.y = __shfl_up(v.q.y, d);
  r.q.z = __shfl_up(v.q.z, d); r.q.w = __shfl_up(v.q.w, d);
  r.s.x = __shfl_up(v.s.x, d); r.s.y = __shfl_up(v.s.y, d);
  r.s.z = __shfl_up(v.s.z, d);
  r.p.x = __shfl_up(v.p.x, d); r.p.y = __shfl_up(v.p.y, d);
  r.p.z = __shfl_up(v.p.z, d);
  r.T   = __shfl_up(v.T, d);   r.pad = 0.0f;
  return r;
}

__device__ __forceinline__ St bcast_st(const St& v, int src) {
  St r;
  r.q.x = __shfl(v.q.x, src); r.q.y = __shfl(v.q.y, src);
  r.q.z = __shfl(v.q.z, src); r.q.w = __shfl(v.q.w, src);
  r.s.x = __shfl(v.s.x, src); r.s.y = __shfl(v.s.y, src);
  r.s.z = __shfl(v.s.z, src);
  r.p.x = __shfl(v.p.x, src); r.p.y = __shfl(v.p.y, src);
  r.p.z = __shfl(v.p.z, src);
  r.T   = __shfl(v.T, src);   r.pad = 0.0f;
  return r;
}

// Swizzle: XOR byte-addr bits 4-5 with bits 8-9 (involution, 16B-preserving,
// bijective per 256 B block). LDS-read side (L4) + GLOBAL SOURCE side for
// global_load_lds (rule #21).
__device__ __forceinline__ int swz(int byteoff) {
  return byteoff ^ (((byteoff >> 8) & 3) << 4);
}
__device__ __forceinline__ float4& L4(float* lds, int fidx) {
  return *reinterpret_cast<float4*>(reinterpret_cast<char*>(lds) + swz(fidx << 2));
}

__device__ __forceinline__ void stage16(const void* gsrc, void* ldst) {
  __builtin_amdgcn_global_load_lds(
      (const __attribute__((address_space(1))) void*)gsrc,
      (__attribute__((address_space(3))) void*)ldst, 16, 0, 0);
}

#define STAGE_REGION(gbase, regionByte, nK)                                    \
  {                                                                            \
    _Pragma("unroll")                                                          \
    for (int k = 0; k < (nK); ++k) {                                           \
      int db = k*1024 + t*16;                                                  \
      const char* src = (const char*)(gbase) + swz(db);                        \
      char* ldst = (char*)lds + (regionByte) + k*1024;                         \
      stage16(src, ldst);                                                      \
    }                                                                          \
  }

// load 4 slim elements from staged LDS; store compressed (cq 12, cs 12, cdt 4)
#define BUILD_SLIM()                                                           \
  float cq[12], cs[12], cdt[4];                                                \
  Q4 segq; V3 segs, segp; float segT;                                          \
  {                                                                            \
    float gy[12], ac[12], gq[16];                                              \
    _Pragma("unroll")                                                          \
    for (int j = 0; j < 3; ++j) ((float4*)gy)[j] = L4(lds, GY_F + 12*t + 4*j); \
    _Pragma("unroll")                                                          \
    for (int j = 0; j < 3; ++j) ((float4*)ac)[j] = L4(lds, AC_F + 12*t + 4*j); \
    _Pragma("unroll")                                                          \
    for (int j = 0; j < 4; ++j) ((float4*)gq)[j] = L4(lds, GT_F + 16*t + 4*j); \
    const float dtv[4] = {dt4.x, dt4.y, dt4.z, dt4.w};                         \
    _Pragma("unroll")                                                          \
    for (int i = 0; i < SEQ; ++i) {                                            \
      El e = elem_state(dtv[i],                                                \
                 {gy[3*i], gy[3*i+1], gy[3*i+2]},                              \
                 {ac[3*i], ac[3*i+1], ac[3*i+2]},                              \
                 {gq[4*i], gq[4*i+1], gq[4*i+2], gq[4*i+3]});                  \
      cq[3*i] = e.q.x; cq[3*i+1] = e.q.y; cq[3*i+2] = e.q.z;                   \
      cs[3*i] = e.s.x; cs[3*i+1] = e.s.y; cs[3*i+2] = e.s.z;                   \
      cdt[i]  = e.dt;                                                          \
      if (i == 0) {                                                            \
        segq = e.q; segs = e.s;                                                \
        float h = 0.5f*e.dt;                                                   \
        segp = { e.s.x*h, e.s.y*h, e.s.z*h };                                  \
        segT = e.dt;                                                           \
      } else {                                                                 \
        V3 v = qrot(segq, e.s);                                                \
        float h = 0.5f*e.dt;                                                   \
        segp.x += segs.x*e.dt + v.x*h;                                         \
        segp.y += segs.y*e.dt + v.y*h;                                         \
        segp.z += segs.z*e.dt + v.z*h;                                         \
        segs.x += v.x; segs.y += v.y; segs.z += v.z;                           \
        segq = qmul(segq, e.q);                                                \
        segT += e.dt;                                                          \
      }                                                                        \
    }                                                                          \
  }

// Split wave scan (order-preserving): quaternion scan + additive scans.
// Produces per-lane EXCLUSIVE (qex, sex, pex, Tex) and lane-63 INCLUSIVE
// (qin, sin_, pin, Tin) of the wave's segments.
#define WAVE_SPLIT_SCAN()                                                      \
  Q4 qin = segq;                                                               \
  _Pragma("unroll")                                                            \
  for (int d = 1; d < 64; d <<= 1) {                                           \
    Q4 o = shfl_up_q(qin, d);                                                  \
    if (t >= d) qin = qmul(o, qin);                                            \
  }                                                                            \
  Q4 qex = shfl_up_q(qin, 1);                                                  \
  if (t == 0) qex = {0.0f, 0.0f, 0.0f, 1.0f};                                  \
  V3 v_  = qrot(qex, segs);                                                    \
  V3 sin_ = v_;                                                                \
  _Pragma("unroll")                                                            \
  for (int d = 1; d < 64; d <<= 1) {                                           \
    V3 o = shfl_up_v(sin_, d);                                                 \
    if (t >= d) { sin_.x += o.x; sin_.y += o.y; sin_.z += o.z; }               \
  }                                                                            \
  V3 sex = shfl_up_v(sin_, 1);                                                 \
  if (t == 0) sex = {0.0f, 0.0f, 0.0f};                                        \
  float Tin = segT;                                                            \
  _Pragma("unroll")                                                            \
  for (int d = 1; d < 64; d <<= 1) {                                           \
    float o = __shfl_up(Tin, d);                                               \
    if (t >= d) Tin += o;                                                      \
  }                                                                            \
  float Tex = __shfl_up(Tin, 1);                                               \
  if (t == 0) Tex = 0.0f;                                                      \
  V3 w_ = qrot(qex, segp);                                                     \
  V3 u_ = { w_.x + sex.x*segT, w_.y + sex.y*segT, w_.z + sex.z*segT };         \
  V3 pin = u_;                                                                 \
  _Pragma("unroll")                                                            \
  for (int d = 1; d < 64; d <<= 1) {                                           \
    V3 o = shfl_up_v(pin, d);                                                  \
    if (t >= d) { pin.x += o.x; pin.y += o.y; pin.z += o.z; }                  \
  }                                                                            \
  V3 pex = shfl_up_v(pin, 1);                                                  \
  if (t == 0) pex = {0.0f, 0.0f, 0.0f};

// Kernel 1: per-chunk aggregates. ONE WAVE PER BLOCK; lane 63's inclusive
// split-scan values ARE the chunk aggregate.
__global__ __launch_bounds__(64) void k_agg(
    const float* __restrict__ dtp, const float* __restrict__ gyp,
    const float* __restrict__ acp, const float* __restrict__ gtp,
    St* __restrict__ aggs)
{
  __shared__ __align__(16) float lds[LDS_F];
  const int t = threadIdx.x;          // == lane
  const size_t base = (size_t)blockIdx.x * WCHUNK;

  STAGE_REGION(gyp + base*3, 0,    3);
  STAGE_REGION(acp + base*3, 3072, 3);
  STAGE_REGION(gtp + base*4, 6144, 4);
  float4 dt4 = ((const float4*)(dtp + base))[t];
  __syncthreads();                    // orders DMA completion vs ds_read

  BUILD_SLIM();
  WAVE_SPLIT_SCAN();

  if (t == 63) {
    St a;
    a.q = qin; a.s = sin_; a.p = pin; a.T = Tin; a.pad = 0.0f;
    aggs[blockIdx.x] = a;
  }
  (void)cq; (void)cs; (void)cdt; (void)qex; (void)sex; (void)pex; (void)Tex;
}

// Kernel 2: exclusive chunk prefixes. One wave per batch row; full-St scan
// (64 waves total -- negligible), cpb in 64-wide windows with carry.
__global__ __launch_bounds__(64) void k_pref(
    const St* __restrict__ aggs, const float* __restrict__ irp,
    float* __restrict__ prefb, int cpb)
{
  const int b = blockIdx.x;
  const int lane = threadIdx.x & 63;

  St carry = identity_st();
  carry.q = { irp[b*4+0], irp[b*4+1], irp[b*4+2], irp[b*4+3] };

  const int nw = (cpb + 63) >> 6;
  for (int w = 0; w < nw; ++w) {
    const int idx = (w << 6) + lane;
    St A = identity_st();
    if (idx < cpb) A = aggs[(size_t)b*cpb + idx];
    #pragma unroll
    for (int d = 1; d < 64; d <<= 1) {
      St o = shfl_up_st(A, d);
      if (lane >= d) A = combine(o, A);
    }
    St ex = shfl_up_st(A, 1);
    St P = (lane == 0) ? carry : combine(carry, ex);
    if (idx < cpb) {
      float4* pp = (float4*)(prefb + ((size_t)b*cpb + idx)*12);
      pp[0] = make_float4(P.q.x, P.q.y, P.q.z, P.q.w);
      pp[1] = make_float4(P.s.x, P.s.y, P.s.z, P.p.x);
      pp[2] = make_float4(P.p.y, P.p.z, P.T, 0.0f);
    }
    carry = combine(carry, bcast_st(A, 63));
  }
}

// Kernel 3: emit. ONE WAVE PER BLOCK. Split scan + split emit loop
// (per element: 1 qmul + 1 qrot instead of a full St combine).
__global__ __launch_bounds__(64) void k_emit(
    const float* __restrict__ dtp, const float* __restrict__ gyp,
    const float* __restrict__ acp, const float* __restrict__ gtp,
    const float* __restrict__ prefb,
    const float* __restrict__ ivp, const float* __restrict__ ipp,
    float* __restrict__ out, int F, int cpb, int B)
{
  __shared__ __align__(16) float lds[LDS_F];
  const int t = threadIdx.x;          // == lane
  const int cid = blockIdx.x;
  const int b = cid / cpb;
  const size_t base = (size_t)cid * WCHUNK;

  // uniform loads first: wave prefix + per-batch vectors
  Q4 Pq; V3 Ps, Pp; float PT;
  {
    const float4* pp = (const float4*)(prefb + (size_t)cid*12);
    float4 a = pp[0], bb = pp[1], cc = pp[2];
    Pq = {a.x, a.y, a.z, a.w};
    Ps = {bb.x, bb.y, bb.z};
    Pp = {bb.w, cc.x, cc.y};
    PT = cc.z;
  }
  V3 iv = { ivp[b*3+0], ivp[b*3+1], ivp[b*3+2] };
  V3 ip = { ipp[b*3+0], ipp[b*3+1], ipp[b*3+2] };

  STAGE_REGION(gyp + base*3, 0,    3);
  STAGE_REGION(acp + base*3, 3072, 3);
  STAGE_REGION(gtp + base*4, 6144, 4);
  float4 dt4 = ((const float4*)(dtp + base))[t];
  __syncthreads();

  BUILD_SLIM();
  WAVE_SPLIT_SCAN();
  (void)qin; (void)sin_; (void)pin; (void)Tin;

  // apply chunk prefix P to this lane's exclusive state: X = P ∘ ex
  Q4 Xq = qmul(Pq, qex);
  V3 rs = qrot(Pq, sex);
  V3 Xs = { Ps.x + rs.x, Ps.y + rs.y, Ps.z + rs.z };
  V3 rp = qrot(Pq, pex);
  V3 Xp = { Pp.x + Ps.x*Tex + rp.x, Pp.y + Ps.y*Tex + rp.y, Pp.z + Ps.z*Tex + rp.z };
  float XT = PT + Tex;

  __syncthreads();   // input reads done; safe to overwrite LDS regions

  // split emit loop into LDS (rot->GT region, vel->GY, pos->AC)
  {
    Q4 qr = Xq; V3 sr = Xs; V3 pr = Xp; float Tr = XT;
    float velb[12], posb[12];
    #pragma unroll
    for (int i = 0; i < SEQ; ++i) {
      float qx = cq[3*i], qy = cq[3*i+1], qz = cq[3*i+2];
      Q4 eq = { qx, qy, qz, sqrtf(fmaxf(1.0f - qx*qx - qy*qy - qz*qz, 0.0f)) };
      V3 es = { cs[3*i], cs[3*i+1], cs[3*i+2] };
      float dt = cdt[i], h = 0.5f*dt;
      V3 vv = qrot(qr, es);
      V3 pn = { pr.x + sr.x*dt + vv.x*h,
                pr.y + sr.y*dt + vv.y*h,
                pr.z + sr.z*dt + vv.z*h };
      V3 sn = { sr.x + vv.x, sr.y + vv.y, sr.z + vv.z };
      Q4 qn = qmul(qr, eq);
      float Tn = Tr + dt;
      L4(lds, GT_F + 4*(4*t + i)) = make_float4(qn.x, qn.y, qn.z, qn.w);
      velb[3*i+0] = iv.x + sn.x;
      velb[3*i+1] = iv.y + sn.y;
      velb[3*i+2] = iv.z + sn.z;
      posb[3*i+0] = ip.x + iv.x*Tn + pn.x;
      posb[3*i+1] = ip.y + iv.y*Tn + pn.y;
      posb[3*i+2] = ip.z + iv.z*Tn + pn.z;
      qr = qn; sr = sn; pr = pn; Tr = Tn;
    }
    #pragma unroll
    for (int j = 0; j < 3; ++j) L4(lds, GY_F + 12*t + 4*j) = ((float4*)velb)[j];
    #pragma unroll
    for (int j = 0; j < 3; ++j) L4(lds, AC_F + 12*t + 4*j) = ((float4*)posb)[j];
  }
  __syncthreads();

  // dense stores (swizzled LDS read matches swizzled writes)
  const size_t BF = (size_t)B * (size_t)F;
  float4* grot = (float4*)out + base;
  float4* gvel = (float4*)(out + BF*4 + base*3);
  float4* gpos = (float4*)(out + BF*7 + base*3);
  #pragma unroll
  for (int k = 0; k < 4; ++k) grot[t + 64*k] = L4(lds, GT_F + 4*(t + 64*k));
  #pragma unroll
  for (int k = 0; k < 3; ++k) gvel[t + 64*k] = L4(lds, GY_F + 4*(t + 64*k));
  #pragma unroll
  for (int k = 0; k < 3; ++k) gpos[t + 64*k] = L4(lds, AC_F + 4*(t + 64*k));
}

} // namespace

extern "C" void kernel_launch(void* const* d_in, const int* in_sizes, int n_in,
                              void* d_out, int out_size, void* d_ws, size_t ws_size,
                              hipStream_t stream)
{
  (void)n_in; (void)out_size; (void)ws_size;

  const float* dtp = (const float*)d_in[0];
  const float* gyp = (const float*)d_in[1];
  const float* acp = (const float*)d_in[2];
  const float* gtp = (const float*)d_in[3];
  const float* irp = (const float*)d_in[4];
  const float* ivp = (const float*)d_in[5];
  const float* ipp = (const float*)d_in[6];
  float* out = (float*)d_out;

  const int B   = in_sizes[4] / 4;    // init_rot has B*4 elements
  const int F   = in_sizes[0] / B;    // dt has B*F elements
  const int cpb = F / WCHUNK;         // 128 for F=32768
  const int nchunk = B * cpb;         // 8192

  St*    aggs  = (St*)d_ws;
  float* prefb = (float*)((char*)d_ws + (size_t)nchunk * sizeof(St));

  k_agg <<<nchunk, 64, 0, stream>>>(dtp, gyp, acp, gtp, aggs);
  k_pref<<<B,      64, 0, stream>>>(aggs, irp, prefb, cpb);
  k_emit<<<nchunk, 64, 0, stream>>>(dtp, gyp, acp, gtp, prefb, ivp, ipp,
                                    out, F, cpb, B);
}